// Round 2
// baseline (413.045 us; speedup 1.0000x reference)
//
#include <hip/hip_runtime.h>

// QuantizedLinear: out = fakequant(x) @ ((qw - zp)*scale).T + bias
// R5: revert to R3's proven 2-phase skeleton (BM=256,BN=128,BK=128, 256 thr,
// 4 m-stacked waves, 48 KB LDS -> 3 blocks/CU, XOR-swizzled staging, measured
// 0 bank conflicts) and switch the MFMA shape 16x16x64 -> 32x32x32 i8:
//   +12% pipe ceiling (4404 vs 3944 TOPS), half the MFMA instruction count
//   for the same ops, same LDS traffic, fewer live operand VGPRs (24 vs 48).
// Quant kernels fused into one grid-stride dispatch (2048 blocks, G11).
//   M = B*S = 8192, N = D_OUT = 4096, K = D_IN = 4096.

typedef __attribute__((ext_vector_type(4)))  int int4v;    // 16 i8 frag
typedef __attribute__((ext_vector_type(16))) int int16v;   // 32x32 acc

#define BM 256
#define BN 128
#define BK 128   // int8 per K-block; 128 B per LDS row

// ---- fused fake-quant x -> int8 and weight (q - zp) -> int8 -------------
// grid-stride, lane-contiguous 16 B per thread per iteration.
__global__ __launch_bounds__(256) void quant_fused_kernel(
    const float4* __restrict__ x,  unsigned int* __restrict__ xq, int n4x,
    const int4*   __restrict__ qw, unsigned int* __restrict__ wq, int n4w,
    const float* __restrict__ act_scale_p, const int* __restrict__ act_zp_p,
    const int* __restrict__ zp_p)
{
    const float s   = act_scale_p[0];
    const float azp = (float)act_zp_p[0];
    const float lo = -azp, hi = 255.0f - azp;
    const int   zp  = zp_p[0];
    const int total  = n4x + n4w;
    const int stride = gridDim.x * blockDim.x;
    for (int g = blockIdx.x * blockDim.x + threadIdx.x; g < total; g += stride) {
        if (g < n4x) {
            float4 v = x[g];
            float f0 = fminf(fmaxf(rintf(v.x / s), lo), hi);  // IEEE div+RNE = jnp.round(x/s)
            float f1 = fminf(fmaxf(rintf(v.y / s), lo), hi);
            float f2 = fminf(fmaxf(rintf(v.z / s), lo), hi);
            float f3 = fminf(fmaxf(rintf(v.w / s), lo), hi);
            unsigned int b0 = (unsigned int)(int)f0 & 0xff;
            unsigned int b1 = (unsigned int)(int)f1 & 0xff;
            unsigned int b2 = (unsigned int)(int)f2 & 0xff;
            unsigned int b3 = (unsigned int)(int)f3 & 0xff;
            xq[g] = b0 | (b1 << 8) | (b2 << 16) | (b3 << 24);
        } else {
            int4 v = qw[g - n4x];
            unsigned int b0 = (unsigned int)(v.x - zp) & 0xff;
            unsigned int b1 = (unsigned int)(v.y - zp) & 0xff;
            unsigned int b2 = (unsigned int)(v.z - zp) & 0xff;
            unsigned int b3 = (unsigned int)(v.w - zp) & 0xff;
            wq[g - n4x] = b0 | (b1 << 8) | (b2 << 16) | (b3 << 24);
        }
    }
}

// ---- int8 GEMM, B^T input (w is [N][K]) ----
// Block 256x128, BK=128. 4 waves m-stacked; each wave 64x128 via 2x4 grid of
// v_mfma_i32_32x32x32_i8 (4 k-steps). global_load_lds width=16 staging.
// LDS swizzle: 16B chunk c of row r stored at chunk slot c ^ (r&7)
//   -> each consecutive-8-lane read group covers 8 distinct slots (conflict-
//      free, measured 0 in R3); staging keeps dst = uniform base + tid*16
//      (global source gets the XOR).
#define ASYNC_CP16(gp, lp)                                                      \
    __builtin_amdgcn_global_load_lds(                                           \
        (const __attribute__((address_space(1))) unsigned int*)(gp),            \
        (__attribute__((address_space(3))) unsigned int*)(lp), 16, 0, 0)

__global__ __launch_bounds__(256, 2) void gemm_i8_kernel(
    const signed char* __restrict__ A,   // [M][K] int8 (xi)
    const signed char* __restrict__ B,   // [N][K] int8 (wi)
    const float* __restrict__ bias,
    const float* __restrict__ scale_p, const float* __restrict__ act_scale_p,
    float* __restrict__ C, int M, int N, int K)
{
    __shared__ __align__(16) signed char As[BM * BK];   // 32 KB
    __shared__ __align__(16) signed char Bs[BN * BK];   // 16 KB

    const int tid  = threadIdx.x;
    const int lane = tid & 63;
    const int wave = tid >> 6;
    const int bm = blockIdx.y * BM;
    const int bn = blockIdx.x * BN;

    // staging: one CP round = 256 threads x 16 B = 4 KB = 32 rows of 128 B.
    // LDS position p = round*256 + tid: row = p>>3, chunk slot = tid&7,
    // holding global chunk (tid&7) ^ (row&7); row&7 == (tid>>3)&7.
    const int srow = tid >> 3;                       // 0..31 within a round
    const int scol = ((tid & 7) ^ (srow & 7)) * 16;  // XOR applied to source
    const signed char* aP = A + (size_t)(bm + srow) * K + scol;
    const signed char* bP = B + (size_t)(bn + srow) * K + scol;
    signed char* asD = &As[(size_t)tid * 16];
    signed char* bsD = &Bs[(size_t)tid * 16];

    const int wm = wave * 64;            // wave's 64-row slice of the 256
    const int fr = lane & 31;            // fragment row (m or n), 32x32 shape
    const int g2 = lane >> 5;            // k-subchunk group 0..1
    const int x7 = lane & 7;             // row-dependent XOR (rows are +32*i)

    int16v acc[2][4] = {};

    for (int k0 = 0; k0 < K; k0 += BK) {
#pragma unroll
        for (int r = 0; r < 8; r++)                       // A: 256 rows
            ASYNC_CP16(aP + (size_t)r * 32 * K, asD + r * 4096);
#pragma unroll
        for (int r = 0; r < 4; r++)                       // B: 128 rows
            ASYNC_CP16(bP + (size_t)r * 32 * K, bsD + r * 4096);
        aP += BK; bP += BK;
        __syncthreads();   // compiler inserts vmcnt(0) drain here

#pragma unroll
        for (int kk = 0; kk < 4; kk++) {                  // 4 k-steps of 32
            const int ko = ((kk * 2 + g2) ^ x7) * 16;
            int4v af[2], bf[4];
#pragma unroll
            for (int i = 0; i < 2; i++)
                af[i] = *(const int4v*)&As[(wm + i * 32 + fr) * BK + ko];
#pragma unroll
            for (int j = 0; j < 4; j++)
                bf[j] = *(const int4v*)&Bs[(j * 32 + fr) * BK + ko];
#pragma unroll
            for (int i = 0; i < 2; i++)
#pragma unroll
                for (int j = 0; j < 4; j++)
                    acc[i][j] = __builtin_amdgcn_mfma_i32_32x32x32_i8(
                        af[i], bf[j], acc[i][j], 0, 0, 0);
        }
        __syncthreads();
    }

    // epilogue: 32x32 C/D layout (m74/m101, dtype-independent):
    //   col = lane&31, row = (reg&3) + 8*(reg>>2) + 4*(lane>>5)
    const float sc = scale_p[0] * act_scale_p[0];
    const int ccol  = lane & 31;
    const int rbase = (lane >> 5) * 4;
#pragma unroll
    for (int i = 0; i < 2; i++) {
        const int m0 = bm + wm + i * 32 + rbase;
#pragma unroll
        for (int j = 0; j < 4; j++) {
            const int n = bn + j * 32 + ccol;
            const float bv = bias[n];
#pragma unroll
            for (int r = 0; r < 16; r++) {
                const int row = (r & 3) + 8 * (r >> 2);
                C[(size_t)(m0 + row) * N + n] = (float)acc[i][j][r] * sc + bv;
            }
        }
    }
}

extern "C" void kernel_launch(void* const* d_in, const int* in_sizes, int n_in,
                              void* d_out, int out_size, void* d_ws, size_t ws_size,
                              hipStream_t stream) {
    const float* x         = (const float*)d_in[0];
    const int*   qw        = (const int*)  d_in[1];
    const float* scale     = (const float*)d_in[2];
    const int*   zp        = (const int*)  d_in[3];
    const float* bias      = (const float*)d_in[4];
    const float* act_scale = (const float*)d_in[5];
    const int*   act_zp    = (const int*)  d_in[6];
    float* out = (float*)d_out;

    const int D_OUT = in_sizes[4];            // bias length
    const int D_IN  = in_sizes[1] / D_OUT;    // qweight is [D_OUT][D_IN]
    const int M = in_sizes[0] / D_IN;
    const int N = D_OUT, K = D_IN;

    signed char* xq = (signed char*)d_ws;                  // [M][K] int8
    signed char* wq = xq + (size_t)M * K;                  // [N][K] int8

    const int n4x = (M * K) / 4;
    const int n4w = (N * K) / 4;
    int qblocks = (n4x + n4w + 255) / 256;
    if (qblocks > 2048) qblocks = 2048;
    quant_fused_kernel<<<qblocks, 256, 0, stream>>>(
        (const float4*)x, (unsigned int*)xq, n4x,
        (const int4*)qw, (unsigned int*)wq, n4w,
        act_scale, act_zp, zp);

    dim3 grid(N / BN, M / BM);
    gemm_i8_kernel<<<grid, 256, 0, stream>>>(xq, wq, bias, scale, act_scale,
                                             out, M, N, K);
}

// Round 3
// 404.112 us; speedup vs baseline: 1.0221x; 1.0221x over previous
//
#include <hip/hip_runtime.h>
#include <hip/hip_bf16.h>

// QuantizedLinear: out = fakequant(x) @ ((qw - zp)*scale).T + bias
// R6: exact revert to the proven R3 configuration (2-phase skeleton,
// BM=256,BN=128,BK=128, 256 thr, 4 m-stacked waves, 16x16x64 i8 MFMA,
// XOR-swizzled global_load_lds staging -> measured 0 bank conflicts,
// gemm 130.6us) + ONE change: T1 XCD-aware chunked block swizzle.
//   Mechanism: FETCH_SIZE 147MB vs 48MB compulsory (C-write stream defeats
//   L3 retention; round-robin block->XCD mapping defeats L2 A-panel reuse).
//   Chunked mapping gives each XCD 4 contiguous block-rows -> A panel (1MB)
//   stays L2-resident across its 32 consumers; staging loads complete from
//   L2 (~200cy) instead of HBM (~900cy), shortening the barrier drain.
//   nwg = 1024, nwg%8==0 -> simple bijective form is valid (ERRATA #11).
//   M = B*S = 8192, N = D_OUT = 4096, K = D_IN = 4096.

typedef __attribute__((ext_vector_type(4))) int int4v;   // 16 int8 frag / 4 i32 acc

#define BM 256
#define BN 128
#define BK 128   // int8 per K-block; 128 B per LDS row

// ---- fake-quant x -> int8, lane-contiguous: 1 float4 per thread ----
__global__ __launch_bounds__(256) void quant_x_kernel(
    const float4* __restrict__ x, unsigned int* __restrict__ xq,
    const float* __restrict__ act_scale_p, const int* __restrict__ act_zp_p,
    int n4)
{
    int g = blockIdx.x * blockDim.x + threadIdx.x;
    if (g >= n4) return;
    const float s   = act_scale_p[0];
    const float azp = (float)act_zp_p[0];
    const float lo = -azp, hi = 255.0f - azp;
    float4 v = x[g];
    float f0 = fminf(fmaxf(rintf(v.x / s), lo), hi);   // IEEE div+RNE = jnp.round(x/s)
    float f1 = fminf(fmaxf(rintf(v.y / s), lo), hi);
    float f2 = fminf(fmaxf(rintf(v.z / s), lo), hi);
    float f3 = fminf(fmaxf(rintf(v.w / s), lo), hi);
    unsigned int b0 = (unsigned int)(int)f0 & 0xff;
    unsigned int b1 = (unsigned int)(int)f1 & 0xff;
    unsigned int b2 = (unsigned int)(int)f2 & 0xff;
    unsigned int b3 = (unsigned int)(int)f3 & 0xff;
    xq[g] = b0 | (b1 << 8) | (b2 << 16) | (b3 << 24);
}

// ---- weight integer part -> int8, lane-contiguous: 1 int4 per thread ----
__global__ __launch_bounds__(256) void quant_w_kernel(
    const int4* __restrict__ qw, unsigned int* __restrict__ wq,
    const int* __restrict__ zp_p, int n4)
{
    int g = blockIdx.x * blockDim.x + threadIdx.x;
    if (g >= n4) return;
    const int zp = zp_p[0];
    int4 v = qw[g];
    unsigned int b0 = (unsigned int)(v.x - zp) & 0xff;
    unsigned int b1 = (unsigned int)(v.y - zp) & 0xff;
    unsigned int b2 = (unsigned int)(v.z - zp) & 0xff;
    unsigned int b3 = (unsigned int)(v.w - zp) & 0xff;
    wq[g] = b0 | (b1 << 8) | (b2 << 16) | (b3 << 24);
}

// ---- int8 GEMM, B^T input (w is [N][K]) ----
// Block 256x128, BK=128. 4 waves m-stacked; each wave 64x128 via 4x8 grid of
// v_mfma_i32_16x16x64_i8 (2 k-steps). global_load_lds width=16 staging.
// LDS swizzle: 16B chunk c of row r stored at chunk slot c ^ (r&7)
//   -> 16-lane fragment groups hit 8 bank-quads 2-way each (free, m136);
//   -> staging keeps dst = uniform base + tid*16 (global source gets the XOR).
#define ASYNC_CP16(gp, lp)                                                      \
    __builtin_amdgcn_global_load_lds(                                           \
        (const __attribute__((address_space(1))) unsigned int*)(gp),            \
        (__attribute__((address_space(3))) unsigned int*)(lp), 16, 0, 0)

__global__ __launch_bounds__(256, 2) void gemm_i8_kernel(
    const signed char* __restrict__ A,   // [M][K] int8 (xi)
    const signed char* __restrict__ B,   // [N][K] int8 (wi)
    const float* __restrict__ bias,
    const float* __restrict__ scale_p, const float* __restrict__ act_scale_p,
    float* __restrict__ C, int M, int N, int K)
{
    __shared__ __align__(16) signed char As[BM * BK];   // 32 KB
    __shared__ __align__(16) signed char Bs[BN * BK];   // 16 KB

    const int tid  = threadIdx.x;
    const int lane = tid & 63;
    const int wave = tid >> 6;

    // T1: XCD-aware chunked block swizzle. Default dispatch round-robins
    // consecutive flat block ids across the 8 XCDs; remap so each XCD owns a
    // contiguous chunk of the (col-fastest) grid -> same-A-row blocks share
    // one XCD's L2. Bijective iff nwg % 8 == 0; otherwise fall back.
    const int nbx = gridDim.x;
    const int nwg = nbx * gridDim.y;
    int bid = blockIdx.y * nbx + blockIdx.x;
    if ((nwg & 7) == 0) {
        const int cpx = nwg >> 3;                 // blocks per XCD chunk
        bid = (bid & 7) * cpx + (bid >> 3);
    }
    const int bm = (bid / nbx) * BM;
    const int bn = (bid % nbx) * BN;

    // staging: one CP round = 256 threads x 16 B = 4 KB = 32 rows of 128 B.
    // LDS position p = round*256 + tid: row = p>>3, chunk slot = tid&7,
    // holding global chunk (tid&7) ^ (row&7); row&7 == (tid>>3)&7.
    const int srow = tid >> 3;                       // 0..31 within a round
    const int scol = ((tid & 7) ^ (srow & 7)) * 16;  // XOR applied to source
    const signed char* aP = A + (size_t)(bm + srow) * K + scol;
    const signed char* bP = B + (size_t)(bn + srow) * K + scol;
    signed char* asD = &As[(size_t)tid * 16];
    signed char* bsD = &Bs[(size_t)tid * 16];

    const int wm = wave * 64;            // wave's 64-row slice of the 256
    const int fr = lane & 15;            // fragment row (m or n)
    const int g4 = lane >> 4;            // k-chunk group 0..3
    const int x7 = fr & 7;               // row-dependent XOR

    int4v acc[4][8] = {};

    for (int k0 = 0; k0 < K; k0 += BK) {
#pragma unroll
        for (int r = 0; r < 8; r++)                       // A: 256 rows
            ASYNC_CP16(aP + (size_t)r * 32 * K, asD + r * 4096);
#pragma unroll
        for (int r = 0; r < 4; r++)                       // B: 128 rows
            ASYNC_CP16(bP + (size_t)r * 32 * K, bsD + r * 4096);
        aP += BK; bP += BK;
        __syncthreads();   // compiler inserts vmcnt(0) drain here

#pragma unroll
        for (int kk = 0; kk < 2; kk++) {
            const int ko = ((kk * 4 + g4) ^ x7) * 16;
            int4v af[4], bf[8];
#pragma unroll
            for (int i = 0; i < 4; i++)
                af[i] = *(const int4v*)&As[(wm + i * 16 + fr) * BK + ko];
#pragma unroll
            for (int j = 0; j < 8; j++)
                bf[j] = *(const int4v*)&Bs[(j * 16 + fr) * BK + ko];
#pragma unroll
            for (int i = 0; i < 4; i++)
#pragma unroll
                for (int j = 0; j < 8; j++)
                    acc[i][j] = __builtin_amdgcn_mfma_i32_16x16x64_i8(
                        af[i], bf[j], acc[i][j], 0, 0, 0);
        }
        __syncthreads();
    }

    // epilogue: C/D layout col=lane&15, row=(lane>>4)*4+reg (dtype-independent)
    const float sc = scale_p[0] * act_scale_p[0];
    const int crow = (lane >> 4) * 4;
    const int ccol = lane & 15;
#pragma unroll
    for (int i = 0; i < 4; i++) {
        const int m = bm + wm + i * 16 + crow;
#pragma unroll
        for (int j = 0; j < 8; j++) {
            const int n = bn + j * 16 + ccol;
            const float bv = bias[n];
#pragma unroll
            for (int r = 0; r < 4; r++) {
                C[(size_t)(m + r) * N + n] = (float)acc[i][j][r] * sc + bv;
            }
        }
    }
}

extern "C" void kernel_launch(void* const* d_in, const int* in_sizes, int n_in,
                              void* d_out, int out_size, void* d_ws, size_t ws_size,
                              hipStream_t stream) {
    const float* x         = (const float*)d_in[0];
    const int*   qw        = (const int*)  d_in[1];
    const float* scale     = (const float*)d_in[2];
    const int*   zp        = (const int*)  d_in[3];
    const float* bias      = (const float*)d_in[4];
    const float* act_scale = (const float*)d_in[5];
    const int*   act_zp    = (const int*)  d_in[6];
    float* out = (float*)d_out;

    const int D_OUT = in_sizes[4];            // bias length
    const int D_IN  = in_sizes[1] / D_OUT;    // qweight is [D_OUT][D_IN]
    const int M = in_sizes[0] / D_IN;
    const int N = D_OUT, K = D_IN;

    signed char* xq = (signed char*)d_ws;                  // [M][K] int8
    signed char* wq = xq + (size_t)M * K;                  // [N][K] int8

    const int n4x = (M * K) / 4;
    quant_x_kernel<<<(n4x + 255) / 256, 256, 0, stream>>>(
        (const float4*)x, (unsigned int*)xq, act_scale, act_zp, n4x);

    const int n4w = (N * K) / 4;
    quant_w_kernel<<<(n4w + 255) / 256, 256, 0, stream>>>(
        (const int4*)qw, (unsigned int*)wq, zp, n4w);

    dim3 grid(N / BN, M / BM);
    gemm_i8_kernel<<<grid, 256, 0, stream>>>(xq, wq, bias, scale, act_scale,
                                             out, M, N, K);
}

// Round 4
// 392.201 us; speedup vs baseline: 1.0531x; 1.0304x over previous
//
#include <hip/hip_runtime.h>
#include <hip/hip_bf16.h>

// QuantizedLinear: out = fakequant(x) @ ((qw - zp)*scale).T + bias
// R7: exact R3 skeleton (the only measured-good structure: 2-phase,
// BM=256,BN=128,BK=128, 256 thr, 4 m-stacked waves, 16x16x64 i8 MFMA,
// XOR-swizzled global_load_lds staging, 0 bank conflicts, gemm 130.6us)
// + ONE change: non-temporal C stores.
//   Mechanism: WRITE_SIZE shows the 131MB f32 C stream flows through L3,
//   evicting the 48MB A+B working set -> FETCH_SIZE 148MB (~3x compulsory)
//   and staging loads miss to HBM (~900cy), lengthening the per-K-tile
//   vmcnt(0) drain that is this structure's stall. R6 proved the re-fetch
//   is NOT an XCD-mapping effect (T1 left FETCH unchanged). nt stores keep
//   C out of L3 -> A/B stay resident -> staging hits cache.
//   M = B*S = 8192, N = D_OUT = 4096, K = D_IN = 4096.

typedef __attribute__((ext_vector_type(4))) int int4v;   // 16 int8 frag / 4 i32 acc

#define BM 256
#define BN 128
#define BK 128   // int8 per K-block; 128 B per LDS row

// ---- fake-quant x -> int8, lane-contiguous: 1 float4 per thread ----
__global__ __launch_bounds__(256) void quant_x_kernel(
    const float4* __restrict__ x, unsigned int* __restrict__ xq,
    const float* __restrict__ act_scale_p, const int* __restrict__ act_zp_p,
    int n4)
{
    int g = blockIdx.x * blockDim.x + threadIdx.x;
    if (g >= n4) return;
    const float s   = act_scale_p[0];
    const float azp = (float)act_zp_p[0];
    const float lo = -azp, hi = 255.0f - azp;
    float4 v = x[g];
    float f0 = fminf(fmaxf(rintf(v.x / s), lo), hi);   // IEEE div+RNE = jnp.round(x/s)
    float f1 = fminf(fmaxf(rintf(v.y / s), lo), hi);
    float f2 = fminf(fmaxf(rintf(v.z / s), lo), hi);
    float f3 = fminf(fmaxf(rintf(v.w / s), lo), hi);
    unsigned int b0 = (unsigned int)(int)f0 & 0xff;
    unsigned int b1 = (unsigned int)(int)f1 & 0xff;
    unsigned int b2 = (unsigned int)(int)f2 & 0xff;
    unsigned int b3 = (unsigned int)(int)f3 & 0xff;
    xq[g] = b0 | (b1 << 8) | (b2 << 16) | (b3 << 24);
}

// ---- weight integer part -> int8, lane-contiguous: 1 int4 per thread ----
__global__ __launch_bounds__(256) void quant_w_kernel(
    const int4* __restrict__ qw, unsigned int* __restrict__ wq,
    const int* __restrict__ zp_p, int n4)
{
    int g = blockIdx.x * blockDim.x + threadIdx.x;
    if (g >= n4) return;
    const int zp = zp_p[0];
    int4 v = qw[g];
    unsigned int b0 = (unsigned int)(v.x - zp) & 0xff;
    unsigned int b1 = (unsigned int)(v.y - zp) & 0xff;
    unsigned int b2 = (unsigned int)(v.z - zp) & 0xff;
    unsigned int b3 = (unsigned int)(v.w - zp) & 0xff;
    wq[g] = b0 | (b1 << 8) | (b2 << 16) | (b3 << 24);
}

// ---- int8 GEMM, B^T input (w is [N][K]) ----
// Block 256x128, BK=128. 4 waves m-stacked; each wave 64x128 via 4x8 grid of
// v_mfma_i32_16x16x64_i8 (2 k-steps). global_load_lds width=16 staging.
// LDS swizzle: 16B chunk c of row r stored at chunk slot c ^ (r&7)
//   -> 16-lane fragment groups hit 8 bank-quads 2-way each (free, m136);
//   -> staging keeps dst = uniform base + tid*16 (global source gets the XOR).
#define ASYNC_CP16(gp, lp)                                                      \
    __builtin_amdgcn_global_load_lds(                                           \
        (const __attribute__((address_space(1))) unsigned int*)(gp),            \
        (__attribute__((address_space(3))) unsigned int*)(lp), 16, 0, 0)

__global__ __launch_bounds__(256, 2) void gemm_i8_kernel(
    const signed char* __restrict__ A,   // [M][K] int8 (xi)
    const signed char* __restrict__ B,   // [N][K] int8 (wi)
    const float* __restrict__ bias,
    const float* __restrict__ scale_p, const float* __restrict__ act_scale_p,
    float* __restrict__ C, int M, int N, int K)
{
    __shared__ __align__(16) signed char As[BM * BK];   // 32 KB
    __shared__ __align__(16) signed char Bs[BN * BK];   // 16 KB

    const int tid  = threadIdx.x;
    const int lane = tid & 63;
    const int wave = tid >> 6;
    const int bm = blockIdx.y * BM;
    const int bn = blockIdx.x * BN;

    // staging: one CP round = 256 threads x 16 B = 4 KB = 32 rows of 128 B.
    // LDS position p = round*256 + tid: row = p>>3, chunk slot = tid&7,
    // holding global chunk (tid&7) ^ (row&7); row&7 == (tid>>3)&7.
    const int srow = tid >> 3;                       // 0..31 within a round
    const int scol = ((tid & 7) ^ (srow & 7)) * 16;  // XOR applied to source
    const signed char* aP = A + (size_t)(bm + srow) * K + scol;
    const signed char* bP = B + (size_t)(bn + srow) * K + scol;
    signed char* asD = &As[(size_t)tid * 16];
    signed char* bsD = &Bs[(size_t)tid * 16];

    const int wm = wave * 64;            // wave's 64-row slice of the 256
    const int fr = lane & 15;            // fragment row (m or n)
    const int g4 = lane >> 4;            // k-chunk group 0..3
    const int x7 = fr & 7;               // row-dependent XOR

    int4v acc[4][8] = {};

    for (int k0 = 0; k0 < K; k0 += BK) {
#pragma unroll
        for (int r = 0; r < 8; r++)                       // A: 256 rows
            ASYNC_CP16(aP + (size_t)r * 32 * K, asD + r * 4096);
#pragma unroll
        for (int r = 0; r < 4; r++)                       // B: 128 rows
            ASYNC_CP16(bP + (size_t)r * 32 * K, bsD + r * 4096);
        aP += BK; bP += BK;
        __syncthreads();   // compiler inserts vmcnt(0) drain here

#pragma unroll
        for (int kk = 0; kk < 2; kk++) {
            const int ko = ((kk * 4 + g4) ^ x7) * 16;
            int4v af[4], bf[8];
#pragma unroll
            for (int i = 0; i < 4; i++)
                af[i] = *(const int4v*)&As[(wm + i * 16 + fr) * BK + ko];
#pragma unroll
            for (int j = 0; j < 8; j++)
                bf[j] = *(const int4v*)&Bs[(j * 16 + fr) * BK + ko];
#pragma unroll
            for (int i = 0; i < 4; i++)
#pragma unroll
                for (int j = 0; j < 8; j++)
                    acc[i][j] = __builtin_amdgcn_mfma_i32_16x16x64_i8(
                        af[i], bf[j], acc[i][j], 0, 0, 0);
        }
        __syncthreads();
    }

    // epilogue: C/D layout col=lane&15, row=(lane>>4)*4+reg (dtype-independent)
    // nt stores: keep the 131MB C stream out of L3 so A/B stay resident.
    const float sc = scale_p[0] * act_scale_p[0];
    const int crow = (lane >> 4) * 4;
    const int ccol = lane & 15;
#pragma unroll
    for (int i = 0; i < 4; i++) {
        const int m = bm + wm + i * 16 + crow;
#pragma unroll
        for (int j = 0; j < 8; j++) {
            const int n = bn + j * 16 + ccol;
            const float bv = bias[n];
#pragma unroll
            for (int r = 0; r < 4; r++) {
                __builtin_nontemporal_store(
                    (float)acc[i][j][r] * sc + bv,
                    &C[(size_t)(m + r) * N + n]);
            }
        }
    }
}

extern "C" void kernel_launch(void* const* d_in, const int* in_sizes, int n_in,
                              void* d_out, int out_size, void* d_ws, size_t ws_size,
                              hipStream_t stream) {
    const float* x         = (const float*)d_in[0];
    const int*   qw        = (const int*)  d_in[1];
    const float* scale     = (const float*)d_in[2];
    const int*   zp        = (const int*)  d_in[3];
    const float* bias      = (const float*)d_in[4];
    const float* act_scale = (const float*)d_in[5];
    const int*   act_zp    = (const int*)  d_in[6];
    float* out = (float*)d_out;

    const int D_OUT = in_sizes[4];            // bias length
    const int D_IN  = in_sizes[1] / D_OUT;    // qweight is [D_OUT][D_IN]
    const int M = in_sizes[0] / D_IN;
    const int N = D_OUT, K = D_IN;

    signed char* xq = (signed char*)d_ws;                  // [M][K] int8
    signed char* wq = xq + (size_t)M * K;                  // [N][K] int8

    const int n4x = (M * K) / 4;
    quant_x_kernel<<<(n4x + 255) / 256, 256, 0, stream>>>(
        (const float4*)x, (unsigned int*)xq, act_scale, act_zp, n4x);

    const int n4w = (N * K) / 4;
    quant_w_kernel<<<(n4w + 255) / 256, 256, 0, stream>>>(
        (const int4*)qw, (unsigned int*)wq, zp, n4w);

    dim3 grid(N / BN, M / BM);
    gemm_i8_kernel<<<grid, 256, 0, stream>>>(xq, wq, bias, scale, act_scale,
                                             out, M, N, K);
}